// Round 22
// baseline (196.362 us; speedup 1.0000x reference)
//
#include <hip/hip_runtime.h>

// FP8 MLP, fully fused:  out = q(relu(q(x)@q(w1)^T)) @ q(w2)^T
// R22 = R21 (dbuf ILP, 1 block/CU, M=128; 166us) + TLP: 1024-thr blocks,
// 16 waves = 4 waves/SIMD. Wave tile 64dh x 32batch -> acc = 32 AGPR (half of
// R21), so full w1+B register double-buffer fits the (1024,4) 128-reg cap
// (~70 arch + 32 acc). R4/R6's 1024-thr spills came from 64-AGPR acc tiles.
// B-frag 32-row pattern br0=wbi*32+l31 is R15-verified; A/w1 dbuf R10/R21-
// verified; fc2 = 8 row-groups x 2 k-halves, R12-verified pair-reduce.

typedef float f32x4 __attribute__((ext_vector_type(4)));
typedef float f32x16 __attribute__((ext_vector_type(16)));

#define DIN 784
#define KP  832          // 13 * 64 (zero-padded K)
#define DH  4096
#define NKS 13
#define NCH 16
#define CHUNK 256
#define MROWS 128

__device__ __forceinline__ unsigned long long q8(float4 a, float4 b) {
  int lo = __builtin_amdgcn_cvt_pk_fp8_f32(a.x, a.y, 0, false);
  lo     = __builtin_amdgcn_cvt_pk_fp8_f32(a.z, a.w, lo, true);
  int hi = __builtin_amdgcn_cvt_pk_fp8_f32(b.x, b.y, 0, false);
  hi     = __builtin_amdgcn_cvt_pk_fp8_f32(b.z, b.w, hi, true);
  return (unsigned long long)(unsigned)lo |
         ((unsigned long long)(unsigned)hi << 32);
}

__device__ __forceinline__ f32x16 zero16() { f32x16 z = {}; return z; }

// ---- w1 quantize: f32 [4096][784] -> fp8, wave-coalesced blocked layout ----
// 16KB block (nch*13+ks). Within: slice=(n>>6)&3 (4KB = 64 dh rows),
// sub-block (tq*2+ai) (1KB; tq=k-half, ai=row-32-group), lane=(hi2*32+l31)*16.
// 16B content: va=q8(w1[n][ks*64+(q&1)*32+(q>>1)*8..+8]), vb = same +16.
// (R10/R21's verified layout, verbatim.)

__global__ __launch_bounds__(256) void quant_w1_k(const float* __restrict__ w1,
                                                  unsigned char* __restrict__ w1qb) {
  int idx = blockIdx.x * 256 + threadIdx.x;       // 4096 n * 52 groups
  int n = idx / 52, g = idx % 52;
  int ks = g >> 2, q = g & 3;
  int kA = ks * 64 + (q & 1) * 32 + (q >> 1) * 8;
  int kB = kA + 16;
  const float* r = w1 + (size_t)n * DIN;
  unsigned long long va = 0ull, vb = 0ull;
  if (kA < DIN) va = q8(*(const float4*)(r + kA), *(const float4*)(r + kA + 4));
  if (kB < DIN) vb = q8(*(const float4*)(r + kB), *(const float4*)(r + kB + 4));
  ulonglong2 v; v.x = va; v.y = vb;
  int slice = (n >> 6) & 3, rr = n & 63, ai = rr >> 5, l31n = rr & 31;
  int hi2 = q >> 1, tq = q & 1;
  size_t off = ((size_t)((n >> 8) * NKS + ks) << 14) + slice * 4096 +
               (tq * 2 + ai) * 1024 + (hi2 * 32 + l31n) * 16;
  *(ulonglong2*)(w1qb + off) = v;
}

__global__ __launch_bounds__(256) void quant_w2_k(const float* __restrict__ w2,
                                                  unsigned char* __restrict__ w2q) {
  int idx = blockIdx.x * 256 + threadIdx.x;       // 16 rows * 256 chunks(16B)
  int r = idx >> 8, c = idx & 255;
  ulonglong2 v; v.x = 0ull; v.y = 0ull;
  if (r < 10) {
    const float* p = w2 + (size_t)r * DH + c * 16;
    v.x = q8(*(const float4*)(p), *(const float4*)(p + 4));
    v.y = q8(*(const float4*)(p + 8), *(const float4*)(p + 12));
  }
  *(ulonglong2*)(w2q + (size_t)r * DH + c * 16) = v;  // rows 10..15 = 0
}

// ------------------------------ fused MLP -----------------------------------

__global__ __launch_bounds__(1024, 4)
void fused_mlp(const float* __restrict__ x,
               const unsigned char* __restrict__ w1qb,
               const unsigned char* __restrict__ w2q,
               float* __restrict__ out) {
  __shared__ unsigned char A[NKS * MROWS * 64];   // 104 KB x-panel, read-only
  __shared__ unsigned char H[MROWS * CHUNK];      // 32 KB

  const int tid = threadIdx.x;
  const int lane = tid & 63;
  const int w  = tid >> 6;          // wave 0..15
  const int l31 = lane & 31;
  const int hi  = lane >> 5;
  const int wdi = w >> 2;           // dh 64-slice (0..3) of the 256-chunk
  const int wbi = w & 3;            // batch 32-quarter
  const long row0 = (long)blockIdx.x * MROWS;

  // ---- prologue: quantize 128 x-rows into the LDS panel ----
  for (int it = 0; it < 7; ++it) {
    int idx = tid + it * 1024;                    // 13*128*4 = 6656 writes
    if (idx < NKS * 512) {
      int ks = idx >> 9, rem = idx & 511, row = rem >> 2, q = rem & 3;
      int kA = ks * 64 + (q & 1) * 32 + (q >> 1) * 8;
      int kB = kA + 16;
      const float* xr = x + (row0 + row) * DIN;
      unsigned long long va = 0ull, vb = 0ull;
      if (kA < DIN) va = q8(*(const float4*)(xr + kA), *(const float4*)(xr + kA + 4));
      if (kB < DIN) vb = q8(*(const float4*)(xr + kB), *(const float4*)(xr + kB + 4));
      ulonglong2 v; v.x = va; v.y = vb;
      int slot = q ^ ((row >> 2) & 3);            // conflict-free involution
      *(ulonglong2*)&A[ks * 8192 + row * 64 + slot * 16] = v;
    }
  }
  __syncthreads();   // panel ready

  // loop-invariant offsets
  const int br0 = wbi * 32 + l31;                           // x batch row
#define SOFF(r_, g_) ((r_) * 64 + ((((g_) ^ (((r_) >> 2) & 3))) << 4))
  const unsigned char* aXlo = &A[SOFF(br0, 2 * hi)];
  const unsigned char* aXhi = &A[SOFF(br0, 2 * hi + 1)];
#undef SOFF
  const int wh = w & 7, kh = w >> 3;                        // fc2: row group, k-half
  const int r2 = wh * 16 + (lane & 15);                     // fc2 batch row
  const int x2 = (lane & 15) << 1;
  const int dh0 = wdi * 64 + 4 * hi;                        // H-write dh bases
  const int dh1 = dh0 + 32;
  const unsigned char* w2p0 = w2q + (size_t)(lane & 15) * DH + kh * 128 +
                              (lane >> 4) * 8;
  const unsigned char* wptr = w1qb + wdi * 4096 + (size_t)lane * 16;

  // w1 register double-buffer (4 x 1KB coalesced wave-loads, 64 dh rows)
  ulonglong2 wb_[4], wbn_[4];
  wb_[0] = *(const ulonglong2*)(wptr);           // (k-half 0, ai=0)
  wb_[1] = *(const ulonglong2*)(wptr + 1024);    // (k-half 0, ai=1)
  wb_[2] = *(const ulonglong2*)(wptr + 2048);    // (k-half 1, ai=0)
  wb_[3] = *(const ulonglong2*)(wptr + 3072);    // (k-half 1, ai=1)

  // B-fragment register double-buffer: current-step x fragments (ks = 0)
  ulonglong2 Bc0 = *(const ulonglong2*)(aXlo);
  ulonglong2 Bc1 = *(const ulonglong2*)(aXhi);

  f32x4 acc2 = {0.f, 0.f, 0.f, 0.f};

#pragma unroll 1
  for (int nch = 0; nch < NCH; ++nch) {
    f32x16 c0 = zero16(), c1 = zero16();
#pragma unroll
    for (int ks = 0; ks < NKS; ++ks) {
      // w1 prefetch for step t+1 (next chunk's tile 0 when ks==12)
      if (ks < NKS - 1 || nch < NCH - 1) {
        const unsigned char* np = wptr + (size_t)((ks + 1) << 14);
        wbn_[0] = *(const ulonglong2*)(np);
        wbn_[1] = *(const ulonglong2*)(np + 1024);
        wbn_[2] = *(const ulonglong2*)(np + 2048);
        wbn_[3] = *(const ulonglong2*)(np + 3072);
      }
      // B prefetch for step t+1: ks wraps 12->0 (panel is nch-invariant)
      const int ksn = (ks == NKS - 1) ? 0 : ks + 1;
      ulonglong2 Bn0 = *(const ulonglong2*)(aXlo + ksn * 8192);
      ulonglong2 Bn1 = *(const ulonglong2*)(aXhi + ksn * 8192);

      __builtin_amdgcn_s_setprio(1);
      c0 = __builtin_amdgcn_mfma_f32_32x32x16_fp8_fp8((long)wb_[0].x, (long)Bc0.x, c0, 0, 0, 0);
      c1 = __builtin_amdgcn_mfma_f32_32x32x16_fp8_fp8((long)wb_[1].x, (long)Bc0.x, c1, 0, 0, 0);
      c0 = __builtin_amdgcn_mfma_f32_32x32x16_fp8_fp8((long)wb_[0].y, (long)Bc0.y, c0, 0, 0, 0);
      c1 = __builtin_amdgcn_mfma_f32_32x32x16_fp8_fp8((long)wb_[1].y, (long)Bc0.y, c1, 0, 0, 0);
      c0 = __builtin_amdgcn_mfma_f32_32x32x16_fp8_fp8((long)wb_[2].x, (long)Bc1.x, c0, 0, 0, 0);
      c1 = __builtin_amdgcn_mfma_f32_32x32x16_fp8_fp8((long)wb_[3].x, (long)Bc1.x, c1, 0, 0, 0);
      c0 = __builtin_amdgcn_mfma_f32_32x32x16_fp8_fp8((long)wb_[2].y, (long)Bc1.y, c0, 0, 0, 0);
      c1 = __builtin_amdgcn_mfma_f32_32x32x16_fp8_fp8((long)wb_[3].y, (long)Bc1.y, c1, 0, 0, 0);
      __builtin_amdgcn_s_setprio(0);

      wb_[0] = wbn_[0]; wb_[1] = wbn_[1];
      wb_[2] = wbn_[2]; wb_[3] = wbn_[3];
      Bc0 = Bn0; Bc1 = Bn1;
    }
    wptr += (size_t)NKS << 14;

    // ---- relu + quantize -> H (dh-in-frag = (reg&3) + 8*(reg>>2) + 4*hi) ----
#define HWR(accv, rbv, dhb)                                                    \
    do {                                                                       \
      _Pragma("unroll") for (int qq = 0; qq < 4; ++qq) {                       \
        int dh_ = (dhb) + 8 * qq;                                              \
        unsigned wv = (unsigned)__builtin_amdgcn_cvt_pk_fp8_f32(               \
            fmaxf((accv)[4*qq+0], 0.f), fmaxf((accv)[4*qq+1], 0.f), 0, false); \
        wv = (unsigned)__builtin_amdgcn_cvt_pk_fp8_f32(                        \
            fmaxf((accv)[4*qq+2], 0.f), fmaxf((accv)[4*qq+3], 0.f), (int)wv, true); \
        int sp_ = (dh_ >> 2) ^ (((rbv) & 15) << 1);                            \
        *(unsigned int*)&H[(rbv) * CHUNK + sp_ * 4] = wv;                      \
      }                                                                        \
    } while (0)
    HWR(c0, br0, dh0);
    HWR(c1, br0, dh1);
#undef HWR
    asm volatile("s_waitcnt lgkmcnt(0)" ::: "memory");
    __builtin_amdgcn_s_barrier();
    asm volatile("" ::: "memory");
    // ---- fc2: 4 MFMAs (16x16x32), wave -> rows wh*16.., k-half kh*128 ----
#pragma unroll
    for (int kk = 0; kk < 4; ++kk) {
      int dhl = kh * 128 + kk * 32 + (lane >> 4) * 8;
      long a2 = *(const long long*)&H[r2 * CHUNK + (((dhl >> 2) ^ x2) << 2)];
      long b2 = *(const long long*)(w2p0 + nch * CHUNK + kk * 32);
      acc2 = __builtin_amdgcn_mfma_f32_16x16x32_fp8_fp8(a2, b2, acc2, 0, 0, 0);
    }
    asm volatile("s_waitcnt lgkmcnt(0)" ::: "memory");
    __builtin_amdgcn_s_barrier();   // H reads done before next chunk's writes
    asm volatile("" ::: "memory");
  }

  // ---- pair-reduce fc2 k-halves (waves wh and wh+8), store out[128][10] ----
  __syncthreads();
  float* red = (float*)&H[0];
  if (kh == 1) {
#pragma unroll
    for (int j = 0; j < 4; ++j)
      red[(wh * 16 + (lane >> 4) * 4 + j) * 16 + (lane & 15)] = acc2[j];
  }
  __syncthreads();
  if (kh == 0 && (lane & 15) < 10) {
#pragma unroll
    for (int j = 0; j < 4; ++j) {
      int rl = wh * 16 + (lane >> 4) * 4 + j;
      out[(row0 + rl) * 10 + (lane & 15)] = acc2[j] + red[rl * 16 + (lane & 15)];
    }
  }
}

extern "C" void kernel_launch(void* const* d_in, const int* in_sizes, int n_in,
                              void* d_out, int out_size, void* d_ws, size_t ws_size,
                              hipStream_t stream) {
  const float* x  = (const float*)d_in[0];
  const float* w1 = (const float*)d_in[1];
  const float* w2 = (const float*)d_in[2];
  float* out = (float*)d_out;

  unsigned char* w1qb = (unsigned char*)d_ws;             // blocked, 3.4MB
  unsigned char* w2q  = w1qb + (size_t)DH * KP;           // [16][4096]

  quant_w1_k<<<(DH * 52) / 256, 256, 0, stream>>>(w1, w1qb);
  quant_w2_k<<<16, 256, 0, stream>>>(w2, w2q);
  fused_mlp<<<32768 / MROWS, 1024, 0, stream>>>(x, w1qb, w2q, out);
}

// Round 23
// 166.042 us; speedup vs baseline: 1.1826x; 1.1826x over previous
//
#include <hip/hip_runtime.h>

// FP8 MLP, fully fused:  out = q(relu(q(x)@q(w1)^T)) @ q(w2)^T
// FINAL (R21 restored — session best: 166.3us bench, VGPR 116, zero spill).
// Structure: M=128 rows/block, 8 waves, 1 block/CU (136KB LDS), barrier-free
// fc1 K-loop: x-panel quantized in-block and persistent in LDS (read-only),
// w1 fragments streamed global->reg from an L2-resident wave-coalesced
// blocked layout (4x1KB loads, register double-buffered), x fragments
// register double-buffered from the LDS panel (reads for ks+1 issued before
// the 16-MFMA burst of ks), AGPR accumulators, conflict-free LDS involution
// g^((r>>2)&3). fc2 fused per 256-dh chunk (2 barriers/chunk only).
// Register-cap lesson (R16/R19/R22): this dbuf set needs >128 regs/wave, so
// it ONLY fits where occupancy is LDS-bound (1 block/CU) - do not re-add
// waves or blocks without removing the double-buffers.

typedef float f32x4 __attribute__((ext_vector_type(4)));
typedef float f32x16 __attribute__((ext_vector_type(16)));

#define DIN 784
#define KP  832          // 13 * 64 (zero-padded K)
#define DH  4096
#define NKS 13
#define NCH 16
#define CHUNK 256
#define MROWS 128

__device__ __forceinline__ unsigned long long q8(float4 a, float4 b) {
  int lo = __builtin_amdgcn_cvt_pk_fp8_f32(a.x, a.y, 0, false);
  lo     = __builtin_amdgcn_cvt_pk_fp8_f32(a.z, a.w, lo, true);
  int hi = __builtin_amdgcn_cvt_pk_fp8_f32(b.x, b.y, 0, false);
  hi     = __builtin_amdgcn_cvt_pk_fp8_f32(b.z, b.w, hi, true);
  return (unsigned long long)(unsigned)lo |
         ((unsigned long long)(unsigned)hi << 32);
}

__device__ __forceinline__ f32x16 zero16() { f32x16 z = {}; return z; }

// ---- w1 quantize: f32 [4096][784] -> fp8, wave-coalesced blocked layout ----
// 16KB block (nch*13+ks). Within: slice=(n>>6)&3 (4KB = 64 dh rows),
// sub-block (tq*2+ai) (1KB; tq=k-half, ai=row-32-group), lane=(hi2*32+l31)*16.
// 16B content: va=q8(w1[n][ks*64+(q&1)*32+(q>>1)*8..+8]), vb = same +16.

__global__ __launch_bounds__(256) void quant_w1_k(const float* __restrict__ w1,
                                                  unsigned char* __restrict__ w1qb) {
  int idx = blockIdx.x * 256 + threadIdx.x;       // 4096 n * 52 groups
  int n = idx / 52, g = idx % 52;
  int ks = g >> 2, q = g & 3;
  int kA = ks * 64 + (q & 1) * 32 + (q >> 1) * 8;
  int kB = kA + 16;
  const float* r = w1 + (size_t)n * DIN;
  unsigned long long va = 0ull, vb = 0ull;
  if (kA < DIN) va = q8(*(const float4*)(r + kA), *(const float4*)(r + kA + 4));
  if (kB < DIN) vb = q8(*(const float4*)(r + kB), *(const float4*)(r + kB + 4));
  ulonglong2 v; v.x = va; v.y = vb;
  int slice = (n >> 6) & 3, rr = n & 63, ai = rr >> 5, l31n = rr & 31;
  int hi2 = q >> 1, tq = q & 1;
  size_t off = ((size_t)((n >> 8) * NKS + ks) << 14) + slice * 4096 +
               (tq * 2 + ai) * 1024 + (hi2 * 32 + l31n) * 16;
  *(ulonglong2*)(w1qb + off) = v;
}

__global__ __launch_bounds__(256) void quant_w2_k(const float* __restrict__ w2,
                                                  unsigned char* __restrict__ w2q) {
  int idx = blockIdx.x * 256 + threadIdx.x;       // 16 rows * 256 chunks(16B)
  int r = idx >> 8, c = idx & 255;
  ulonglong2 v; v.x = 0ull; v.y = 0ull;
  if (r < 10) {
    const float* p = w2 + (size_t)r * DH + c * 16;
    v.x = q8(*(const float4*)(p), *(const float4*)(p + 4));
    v.y = q8(*(const float4*)(p + 8), *(const float4*)(p + 12));
  }
  *(ulonglong2*)(w2q + (size_t)r * DH + c * 16) = v;  // rows 10..15 = 0
}

// ------------------------------ fused MLP -----------------------------------

__global__ __launch_bounds__(512, 1)
void fused_mlp(const float* __restrict__ x,
               const unsigned char* __restrict__ w1qb,
               const unsigned char* __restrict__ w2q,
               float* __restrict__ out) {
  __shared__ unsigned char A[NKS * MROWS * 64];   // 104 KB x-panel, read-only
  __shared__ unsigned char H[MROWS * CHUNK];      // 32 KB

  const int tid = threadIdx.x;
  const int lane = tid & 63;
  const int w  = tid >> 6;          // wave 0..7
  const int l31 = lane & 31;
  const int hi  = lane >> 5;
  const int wdi = w >> 1;           // dh 64-slice (0..3) of the 256-chunk
  const int wbi = w & 1;            // batch 64-half
  const long row0 = (long)blockIdx.x * MROWS;

  // ---- prologue: quantize 128 x-rows into the LDS panel ----
  for (int it = 0; it < 13; ++it) {
    int idx = tid + it * 512;                     // 13*128*4 = 6656 exactly
    int ks = idx >> 9, rem = idx & 511, row = rem >> 2, q = rem & 3;
    int kA = ks * 64 + (q & 1) * 32 + (q >> 1) * 8;
    int kB = kA + 16;
    const float* xr = x + (row0 + row) * DIN;
    unsigned long long va = 0ull, vb = 0ull;
    if (kA < DIN) va = q8(*(const float4*)(xr + kA), *(const float4*)(xr + kA + 4));
    if (kB < DIN) vb = q8(*(const float4*)(xr + kB), *(const float4*)(xr + kB + 4));
    ulonglong2 v; v.x = va; v.y = vb;
    int slot = q ^ ((row >> 2) & 3);              // conflict-free involution
    *(ulonglong2*)&A[ks * 8192 + row * 64 + slot * 16] = v;
  }
  __syncthreads();   // panel ready

  // loop-invariant offsets
  const int br0 = wbi * 64 + l31, br1 = br0 + 32;           // x batch rows
#define SOFF(r_, g_) ((r_) * 64 + ((((g_) ^ (((r_) >> 2) & 3))) << 4))
  const unsigned char* aXlo0 = &A[SOFF(br0, 2 * hi)];
  const unsigned char* aXhi0 = &A[SOFF(br0, 2 * hi + 1)];
  const unsigned char* aXlo1 = &A[SOFF(br1, 2 * hi)];
  const unsigned char* aXhi1 = &A[SOFF(br1, 2 * hi + 1)];
#undef SOFF
  const int r2 = w * 16 + (lane & 15);                      // fc2 batch row
  const int x2 = (lane & 15) << 1;
  const int dh0 = wdi * 64 + 4 * hi;                        // H-write dh bases
  const int dh1 = dh0 + 32;
  const unsigned char* w2p0 = w2q + (size_t)(lane & 15) * DH + (lane >> 4) * 8;
  const unsigned char* wptr = w1qb + wdi * 4096 + (size_t)lane * 16;

  // w1 register double-buffer (4 x 1KB coalesced wave-loads)
  ulonglong2 wb_[4], wbn_[4];
  wb_[0] = *(const ulonglong2*)(wptr);           // (k-half 0, ai=0)
  wb_[1] = *(const ulonglong2*)(wptr + 1024);    // (k-half 0, ai=1)
  wb_[2] = *(const ulonglong2*)(wptr + 2048);    // (k-half 1, ai=0)
  wb_[3] = *(const ulonglong2*)(wptr + 3072);    // (k-half 1, ai=1)

  // B-fragment register double-buffer: current-step x fragments (ks = 0)
  ulonglong2 Bc0 = *(const ulonglong2*)(aXlo0);
  ulonglong2 Bc1 = *(const ulonglong2*)(aXhi0);
  ulonglong2 Bc2 = *(const ulonglong2*)(aXlo1);
  ulonglong2 Bc3 = *(const ulonglong2*)(aXhi1);

  f32x4 acc2 = {0.f, 0.f, 0.f, 0.f};

#pragma unroll 1
  for (int nch = 0; nch < NCH; ++nch) {
    // hoist fc2 w2 fragments for this chunk (registers are free at 1 blk/CU)
    long b2v[8];
#pragma unroll
    for (int kk = 0; kk < 8; ++kk)
      b2v[kk] = *(const long long*)(w2p0 + nch * CHUNK + kk * 32);

    f32x16 c00 = zero16(), c01 = zero16(), c10 = zero16(), c11 = zero16();
#pragma unroll
    for (int ks = 0; ks < NKS; ++ks) {
      // w1 prefetch for step t+1 (next chunk's tile 0 when ks==12)
      if (ks < NKS - 1 || nch < NCH - 1) {
        const unsigned char* np = wptr + (size_t)((ks + 1) << 14);
        wbn_[0] = *(const ulonglong2*)(np);
        wbn_[1] = *(const ulonglong2*)(np + 1024);
        wbn_[2] = *(const ulonglong2*)(np + 2048);
        wbn_[3] = *(const ulonglong2*)(np + 3072);
      }
      // B prefetch for step t+1: ks wraps 12->0 (panel is nch-invariant)
      const int ksn = (ks == NKS - 1) ? 0 : ks + 1;
      ulonglong2 Bn0 = *(const ulonglong2*)(aXlo0 + ksn * 8192);
      ulonglong2 Bn1 = *(const ulonglong2*)(aXhi0 + ksn * 8192);
      ulonglong2 Bn2 = *(const ulonglong2*)(aXlo1 + ksn * 8192);
      ulonglong2 Bn3 = *(const ulonglong2*)(aXhi1 + ksn * 8192);

      __builtin_amdgcn_s_setprio(1);
      c00 = __builtin_amdgcn_mfma_f32_32x32x16_fp8_fp8((long)wb_[0].x, (long)Bc0.x, c00, 0, 0, 0);
      c01 = __builtin_amdgcn_mfma_f32_32x32x16_fp8_fp8((long)wb_[0].x, (long)Bc2.x, c01, 0, 0, 0);
      c10 = __builtin_amdgcn_mfma_f32_32x32x16_fp8_fp8((long)wb_[1].x, (long)Bc0.x, c10, 0, 0, 0);
      c11 = __builtin_amdgcn_mfma_f32_32x32x16_fp8_fp8((long)wb_[1].x, (long)Bc2.x, c11, 0, 0, 0);
      c00 = __builtin_amdgcn_mfma_f32_32x32x16_fp8_fp8((long)wb_[0].y, (long)Bc0.y, c00, 0, 0, 0);
      c01 = __builtin_amdgcn_mfma_f32_32x32x16_fp8_fp8((long)wb_[0].y, (long)Bc2.y, c01, 0, 0, 0);
      c10 = __builtin_amdgcn_mfma_f32_32x32x16_fp8_fp8((long)wb_[1].y, (long)Bc0.y, c10, 0, 0, 0);
      c11 = __builtin_amdgcn_mfma_f32_32x32x16_fp8_fp8((long)wb_[1].y, (long)Bc2.y, c11, 0, 0, 0);
      c00 = __builtin_amdgcn_mfma_f32_32x32x16_fp8_fp8((long)wb_[2].x, (long)Bc1.x, c00, 0, 0, 0);
      c01 = __builtin_amdgcn_mfma_f32_32x32x16_fp8_fp8((long)wb_[2].x, (long)Bc3.x, c01, 0, 0, 0);
      c10 = __builtin_amdgcn_mfma_f32_32x32x16_fp8_fp8((long)wb_[3].x, (long)Bc1.x, c10, 0, 0, 0);
      c11 = __builtin_amdgcn_mfma_f32_32x32x16_fp8_fp8((long)wb_[3].x, (long)Bc3.x, c11, 0, 0, 0);
      c00 = __builtin_amdgcn_mfma_f32_32x32x16_fp8_fp8((long)wb_[2].y, (long)Bc1.y, c00, 0, 0, 0);
      c01 = __builtin_amdgcn_mfma_f32_32x32x16_fp8_fp8((long)wb_[2].y, (long)Bc3.y, c01, 0, 0, 0);
      c10 = __builtin_amdgcn_mfma_f32_32x32x16_fp8_fp8((long)wb_[3].y, (long)Bc1.y, c10, 0, 0, 0);
      c11 = __builtin_amdgcn_mfma_f32_32x32x16_fp8_fp8((long)wb_[3].y, (long)Bc3.y, c11, 0, 0, 0);
      __builtin_amdgcn_s_setprio(0);

      wb_[0] = wbn_[0]; wb_[1] = wbn_[1];
      wb_[2] = wbn_[2]; wb_[3] = wbn_[3];
      Bc0 = Bn0; Bc1 = Bn1; Bc2 = Bn2; Bc3 = Bn3;
    }
    wptr += (size_t)NKS << 14;

    // ---- relu + quantize -> H (dh-in-frag = (reg&3) + 8*(reg>>2) + 4*hi) ----
#define HWR(accv, rbv, dhb)                                                    \
    do {                                                                       \
      _Pragma("unroll") for (int qq = 0; qq < 4; ++qq) {                       \
        int dh_ = (dhb) + 8 * qq;                                              \
        unsigned wv = (unsigned)__builtin_amdgcn_cvt_pk_fp8_f32(               \
            fmaxf((accv)[4*qq+0], 0.f), fmaxf((accv)[4*qq+1], 0.f), 0, false); \
        wv = (unsigned)__builtin_amdgcn_cvt_pk_fp8_f32(                        \
            fmaxf((accv)[4*qq+2], 0.f), fmaxf((accv)[4*qq+3], 0.f), (int)wv, true); \
        int sp_ = (dh_ >> 2) ^ (((rbv) & 15) << 1);                            \
        *(unsigned int*)&H[(rbv) * CHUNK + sp_ * 4] = wv;                      \
      }                                                                        \
    } while (0)
    HWR(c00, br0, dh0);
    HWR(c01, br1, dh0);
    HWR(c10, br0, dh1);
    HWR(c11, br1, dh1);
#undef HWR
    asm volatile("s_waitcnt lgkmcnt(0)" ::: "memory");
    __builtin_amdgcn_s_barrier();
    asm volatile("" ::: "memory");
    // ---- fc2: 8 MFMAs (16x16x32), wave w -> rows w*16..w*16+15, full 256k ----
#pragma unroll
    for (int kk = 0; kk < 8; ++kk) {
      int dhl = kk * 32 + (lane >> 4) * 8;
      long a2 = *(const long long*)&H[r2 * CHUNK + (((dhl >> 2) ^ x2) << 2)];
      acc2 = __builtin_amdgcn_mfma_f32_16x16x32_fp8_fp8(a2, b2v[kk], acc2, 0, 0, 0);
    }
    asm volatile("s_waitcnt lgkmcnt(0)" ::: "memory");
    __builtin_amdgcn_s_barrier();   // H reads done before next chunk's writes
    asm volatile("" ::: "memory");
  }

  // ---- store out[128][10]: wave w rows w*16.., col = lane&15 ----
  if ((lane & 15) < 10) {
#pragma unroll
    for (int j = 0; j < 4; ++j) {
      int rl = w * 16 + (lane >> 4) * 4 + j;
      out[(row0 + rl) * 10 + (lane & 15)] = acc2[j];
    }
  }
}

extern "C" void kernel_launch(void* const* d_in, const int* in_sizes, int n_in,
                              void* d_out, int out_size, void* d_ws, size_t ws_size,
                              hipStream_t stream) {
  const float* x  = (const float*)d_in[0];
  const float* w1 = (const float*)d_in[1];
  const float* w2 = (const float*)d_in[2];
  float* out = (float*)d_out;

  unsigned char* w1qb = (unsigned char*)d_ws;             // blocked, 3.4MB
  unsigned char* w2q  = w1qb + (size_t)DH * KP;           // [16][4096]

  quant_w1_k<<<(DH * 52) / 256, 256, 0, stream>>>(w1, w1qb);
  quant_w2_k<<<16, 256, 0, stream>>>(w2, w2q);
  fused_mlp<<<32768 / MROWS, 512, 0, stream>>>(x, w1qb, w2q, out);
}

// Round 24
// 165.848 us; speedup vs baseline: 1.1840x; 1.0012x over previous
//
#include <hip/hip_runtime.h>

// FP8 MLP, fully fused:  out = q(relu(q(x)@q(w1)^T)) @ q(w2)^T
// FINAL (R21 structure; session best, reproduced twice: 166.3 / 166.0 us).
// Structure: M=128 rows/block, 8 waves, 1 block/CU (136KB LDS), barrier-free
// fc1 K-loop: x-panel quantized in-block and persistent in LDS (read-only),
// w1 fragments streamed global->reg from an L2-resident wave-coalesced
// blocked layout (4x1KB loads, register double-buffered), x fragments
// register double-buffered from the LDS panel (reads for ks+1 issued before
// the 16-MFMA burst of ks), AGPR accumulators, conflict-free LDS involution
// g^((r>>2)&3). fc2 fused per 256-dh chunk (2 barriers/chunk only).
// Register-cap lesson (R16/R19/R22): this dbuf set needs >128 regs/wave, so
// it ONLY fits where occupancy is LDS-bound (1 block/CU) - do not re-add
// waves or blocks without removing the double-buffers.

typedef float f32x4 __attribute__((ext_vector_type(4)));
typedef float f32x16 __attribute__((ext_vector_type(16)));

#define DIN 784
#define KP  832          // 13 * 64 (zero-padded K)
#define DH  4096
#define NKS 13
#define NCH 16
#define CHUNK 256
#define MROWS 128

__device__ __forceinline__ unsigned long long q8(float4 a, float4 b) {
  int lo = __builtin_amdgcn_cvt_pk_fp8_f32(a.x, a.y, 0, false);
  lo     = __builtin_amdgcn_cvt_pk_fp8_f32(a.z, a.w, lo, true);
  int hi = __builtin_amdgcn_cvt_pk_fp8_f32(b.x, b.y, 0, false);
  hi     = __builtin_amdgcn_cvt_pk_fp8_f32(b.z, b.w, hi, true);
  return (unsigned long long)(unsigned)lo |
         ((unsigned long long)(unsigned)hi << 32);
}

__device__ __forceinline__ f32x16 zero16() { f32x16 z = {}; return z; }

// ---- w1 quantize: f32 [4096][784] -> fp8, wave-coalesced blocked layout ----
// 16KB block (nch*13+ks). Within: slice=(n>>6)&3 (4KB = 64 dh rows),
// sub-block (tq*2+ai) (1KB; tq=k-half, ai=row-32-group), lane=(hi2*32+l31)*16.
// 16B content: va=q8(w1[n][ks*64+(q&1)*32+(q>>1)*8..+8]), vb = same +16.

__global__ __launch_bounds__(256) void quant_w1_k(const float* __restrict__ w1,
                                                  unsigned char* __restrict__ w1qb) {
  int idx = blockIdx.x * 256 + threadIdx.x;       // 4096 n * 52 groups
  int n = idx / 52, g = idx % 52;
  int ks = g >> 2, q = g & 3;
  int kA = ks * 64 + (q & 1) * 32 + (q >> 1) * 8;
  int kB = kA + 16;
  const float* r = w1 + (size_t)n * DIN;
  unsigned long long va = 0ull, vb = 0ull;
  if (kA < DIN) va = q8(*(const float4*)(r + kA), *(const float4*)(r + kA + 4));
  if (kB < DIN) vb = q8(*(const float4*)(r + kB), *(const float4*)(r + kB + 4));
  ulonglong2 v; v.x = va; v.y = vb;
  int slice = (n >> 6) & 3, rr = n & 63, ai = rr >> 5, l31n = rr & 31;
  int hi2 = q >> 1, tq = q & 1;
  size_t off = ((size_t)((n >> 8) * NKS + ks) << 14) + slice * 4096 +
               (tq * 2 + ai) * 1024 + (hi2 * 32 + l31n) * 16;
  *(ulonglong2*)(w1qb + off) = v;
}

__global__ __launch_bounds__(256) void quant_w2_k(const float* __restrict__ w2,
                                                  unsigned char* __restrict__ w2q) {
  int idx = blockIdx.x * 256 + threadIdx.x;       // 16 rows * 256 chunks(16B)
  int r = idx >> 8, c = idx & 255;
  ulonglong2 v; v.x = 0ull; v.y = 0ull;
  if (r < 10) {
    const float* p = w2 + (size_t)r * DH + c * 16;
    v.x = q8(*(const float4*)(p), *(const float4*)(p + 4));
    v.y = q8(*(const float4*)(p + 8), *(const float4*)(p + 12));
  }
  *(ulonglong2*)(w2q + (size_t)r * DH + c * 16) = v;  // rows 10..15 = 0
}

// ------------------------------ fused MLP -----------------------------------

__global__ __launch_bounds__(512, 1)
void fused_mlp(const float* __restrict__ x,
               const unsigned char* __restrict__ w1qb,
               const unsigned char* __restrict__ w2q,
               float* __restrict__ out) {
  __shared__ unsigned char A[NKS * MROWS * 64];   // 104 KB x-panel, read-only
  __shared__ unsigned char H[MROWS * CHUNK];      // 32 KB

  const int tid = threadIdx.x;
  const int lane = tid & 63;
  const int w  = tid >> 6;          // wave 0..7
  const int l31 = lane & 31;
  const int hi  = lane >> 5;
  const int wdi = w >> 1;           // dh 64-slice (0..3) of the 256-chunk
  const int wbi = w & 1;            // batch 64-half
  const long row0 = (long)blockIdx.x * MROWS;

  // ---- prologue: quantize 128 x-rows into the LDS panel ----
  for (int it = 0; it < 13; ++it) {
    int idx = tid + it * 512;                     // 13*128*4 = 6656 exactly
    int ks = idx >> 9, rem = idx & 511, row = rem >> 2, q = rem & 3;
    int kA = ks * 64 + (q & 1) * 32 + (q >> 1) * 8;
    int kB = kA + 16;
    const float* xr = x + (row0 + row) * DIN;
    unsigned long long va = 0ull, vb = 0ull;
    if (kA < DIN) va = q8(*(const float4*)(xr + kA), *(const float4*)(xr + kA + 4));
    if (kB < DIN) vb = q8(*(const float4*)(xr + kB), *(const float4*)(xr + kB + 4));
    ulonglong2 v; v.x = va; v.y = vb;
    int slot = q ^ ((row >> 2) & 3);              // conflict-free involution
    *(ulonglong2*)&A[ks * 8192 + row * 64 + slot * 16] = v;
  }
  __syncthreads();   // panel ready

  // loop-invariant offsets
  const int br0 = wbi * 64 + l31, br1 = br0 + 32;           // x batch rows
#define SOFF(r_, g_) ((r_) * 64 + ((((g_) ^ (((r_) >> 2) & 3))) << 4))
  const unsigned char* aXlo0 = &A[SOFF(br0, 2 * hi)];
  const unsigned char* aXhi0 = &A[SOFF(br0, 2 * hi + 1)];
  const unsigned char* aXlo1 = &A[SOFF(br1, 2 * hi)];
  const unsigned char* aXhi1 = &A[SOFF(br1, 2 * hi + 1)];
#undef SOFF
  const int r2 = w * 16 + (lane & 15);                      // fc2 batch row
  const int x2 = (lane & 15) << 1;
  const int dh0 = wdi * 64 + 4 * hi;                        // H-write dh bases
  const int dh1 = dh0 + 32;
  const unsigned char* w2p0 = w2q + (size_t)(lane & 15) * DH + (lane >> 4) * 8;
  const unsigned char* wptr = w1qb + wdi * 4096 + (size_t)lane * 16;

  // w1 register double-buffer (4 x 1KB coalesced wave-loads)
  ulonglong2 wb_[4], wbn_[4];
  wb_[0] = *(const ulonglong2*)(wptr);           // (k-half 0, ai=0)
  wb_[1] = *(const ulonglong2*)(wptr + 1024);    // (k-half 0, ai=1)
  wb_[2] = *(const ulonglong2*)(wptr + 2048);    // (k-half 1, ai=0)
  wb_[3] = *(const ulonglong2*)(wptr + 3072);    // (k-half 1, ai=1)

  // B-fragment register double-buffer: current-step x fragments (ks = 0)
  ulonglong2 Bc0 = *(const ulonglong2*)(aXlo0);
  ulonglong2 Bc1 = *(const ulonglong2*)(aXhi0);
  ulonglong2 Bc2 = *(const ulonglong2*)(aXlo1);
  ulonglong2 Bc3 = *(const ulonglong2*)(aXhi1);

  f32x4 acc2 = {0.f, 0.f, 0.f, 0.f};

#pragma unroll 1
  for (int nch = 0; nch < NCH; ++nch) {
    // hoist fc2 w2 fragments for this chunk (registers are free at 1 blk/CU)
    long b2v[8];
#pragma unroll
    for (int kk = 0; kk < 8; ++kk)
      b2v[kk] = *(const long long*)(w2p0 + nch * CHUNK + kk * 32);

    f32x16 c00 = zero16(), c01 = zero16(), c10 = zero16(), c11 = zero16();
#pragma unroll
    for (int ks = 0; ks < NKS; ++ks) {
      // w1 prefetch for step t+1 (next chunk's tile 0 when ks==12)
      if (ks < NKS - 1 || nch < NCH - 1) {
        const unsigned char* np = wptr + (size_t)((ks + 1) << 14);
        wbn_[0] = *(const ulonglong2*)(np);
        wbn_[1] = *(const ulonglong2*)(np + 1024);
        wbn_[2] = *(const ulonglong2*)(np + 2048);
        wbn_[3] = *(const ulonglong2*)(np + 3072);
      }
      // B prefetch for step t+1: ks wraps 12->0 (panel is nch-invariant)
      const int ksn = (ks == NKS - 1) ? 0 : ks + 1;
      ulonglong2 Bn0 = *(const ulonglong2*)(aXlo0 + ksn * 8192);
      ulonglong2 Bn1 = *(const ulonglong2*)(aXhi0 + ksn * 8192);
      ulonglong2 Bn2 = *(const ulonglong2*)(aXlo1 + ksn * 8192);
      ulonglong2 Bn3 = *(const ulonglong2*)(aXhi1 + ksn * 8192);

      __builtin_amdgcn_s_setprio(1);
      c00 = __builtin_amdgcn_mfma_f32_32x32x16_fp8_fp8((long)wb_[0].x, (long)Bc0.x, c00, 0, 0, 0);
      c01 = __builtin_amdgcn_mfma_f32_32x32x16_fp8_fp8((long)wb_[0].x, (long)Bc2.x, c01, 0, 0, 0);
      c10 = __builtin_amdgcn_mfma_f32_32x32x16_fp8_fp8((long)wb_[1].x, (long)Bc0.x, c10, 0, 0, 0);
      c11 = __builtin_amdgcn_mfma_f32_32x32x16_fp8_fp8((long)wb_[1].x, (long)Bc2.x, c11, 0, 0, 0);
      c00 = __builtin_amdgcn_mfma_f32_32x32x16_fp8_fp8((long)wb_[0].y, (long)Bc0.y, c00, 0, 0, 0);
      c01 = __builtin_amdgcn_mfma_f32_32x32x16_fp8_fp8((long)wb_[0].y, (long)Bc2.y, c01, 0, 0, 0);
      c10 = __builtin_amdgcn_mfma_f32_32x32x16_fp8_fp8((long)wb_[1].y, (long)Bc0.y, c10, 0, 0, 0);
      c11 = __builtin_amdgcn_mfma_f32_32x32x16_fp8_fp8((long)wb_[1].y, (long)Bc2.y, c11, 0, 0, 0);
      c00 = __builtin_amdgcn_mfma_f32_32x32x16_fp8_fp8((long)wb_[2].x, (long)Bc1.x, c00, 0, 0, 0);
      c01 = __builtin_amdgcn_mfma_f32_32x32x16_fp8_fp8((long)wb_[2].x, (long)Bc3.x, c01, 0, 0, 0);
      c10 = __builtin_amdgcn_mfma_f32_32x32x16_fp8_fp8((long)wb_[3].x, (long)Bc1.x, c10, 0, 0, 0);
      c11 = __builtin_amdgcn_mfma_f32_32x32x16_fp8_fp8((long)wb_[3].x, (long)Bc3.x, c11, 0, 0, 0);
      c00 = __builtin_amdgcn_mfma_f32_32x32x16_fp8_fp8((long)wb_[2].y, (long)Bc1.y, c00, 0, 0, 0);
      c01 = __builtin_amdgcn_mfma_f32_32x32x16_fp8_fp8((long)wb_[2].y, (long)Bc3.y, c01, 0, 0, 0);
      c10 = __builtin_amdgcn_mfma_f32_32x32x16_fp8_fp8((long)wb_[3].y, (long)Bc1.y, c10, 0, 0, 0);
      c11 = __builtin_amdgcn_mfma_f32_32x32x16_fp8_fp8((long)wb_[3].y, (long)Bc3.y, c11, 0, 0, 0);
      __builtin_amdgcn_s_setprio(0);

      wb_[0] = wbn_[0]; wb_[1] = wbn_[1];
      wb_[2] = wbn_[2]; wb_[3] = wbn_[3];
      Bc0 = Bn0; Bc1 = Bn1; Bc2 = Bn2; Bc3 = Bn3;
    }
    wptr += (size_t)NKS << 14;

    // ---- relu + quantize -> H (dh-in-frag = (reg&3) + 8*(reg>>2) + 4*hi) ----
#define HWR(accv, rbv, dhb)                                                    \
    do {                                                                       \
      _Pragma("unroll") for (int qq = 0; qq < 4; ++qq) {                       \
        int dh_ = (dhb) + 8 * qq;                                              \
        unsigned wv = (unsigned)__builtin_amdgcn_cvt_pk_fp8_f32(               \
            fmaxf((accv)[4*qq+0], 0.f), fmaxf((accv)[4*qq+1], 0.f), 0, false); \
        wv = (unsigned)__builtin_amdgcn_cvt_pk_fp8_f32(                        \
            fmaxf((accv)[4*qq+2], 0.f), fmaxf((accv)[4*qq+3], 0.f), (int)wv, true); \
        int sp_ = (dh_ >> 2) ^ (((rbv) & 15) << 1);                            \
        *(unsigned int*)&H[(rbv) * CHUNK + sp_ * 4] = wv;                      \
      }                                                                        \
    } while (0)
    HWR(c00, br0, dh0);
    HWR(c01, br1, dh0);
    HWR(c10, br0, dh1);
    HWR(c11, br1, dh1);
#undef HWR
    asm volatile("s_waitcnt lgkmcnt(0)" ::: "memory");
    __builtin_amdgcn_s_barrier();
    asm volatile("" ::: "memory");
    // ---- fc2: 8 MFMAs (16x16x32), wave w -> rows w*16..w*16+15, full 256k ----
#pragma unroll
    for (int kk = 0; kk < 8; ++kk) {
      int dhl = kk * 32 + (lane >> 4) * 8;
      long a2 = *(const long long*)&H[r2 * CHUNK + (((dhl >> 2) ^ x2) << 2)];
      acc2 = __builtin_amdgcn_mfma_f32_16x16x32_fp8_fp8(a2, b2v[kk], acc2, 0, 0, 0);
    }
    asm volatile("s_waitcnt lgkmcnt(0)" ::: "memory");
    __builtin_amdgcn_s_barrier();   // H reads done before next chunk's writes
    asm volatile("" ::: "memory");
  }

  // ---- store out[128][10]: wave w rows w*16.., col = lane&15 ----
  if ((lane & 15) < 10) {
#pragma unroll
    for (int j = 0; j < 4; ++j) {
      int rl = w * 16 + (lane >> 4) * 4 + j;
      out[(row0 + rl) * 10 + (lane & 15)] = acc2[j];
    }
  }
}

extern "C" void kernel_launch(void* const* d_in, const int* in_sizes, int n_in,
                              void* d_out, int out_size, void* d_ws, size_t ws_size,
                              hipStream_t stream) {
  const float* x  = (const float*)d_in[0];
  const float* w1 = (const float*)d_in[1];
  const float* w2 = (const float*)d_in[2];
  float* out = (float*)d_out;

  unsigned char* w1qb = (unsigned char*)d_ws;             // blocked, 3.4MB
  unsigned char* w2q  = w1qb + (size_t)DH * KP;           // [16][4096]

  quant_w1_k<<<(DH * 52) / 256, 256, 0, stream>>>(w1, w1qb);
  quant_w2_k<<<16, 256, 0, stream>>>(w2, w2q);
  fused_mlp<<<32768 / MROWS, 512, 0, stream>>>(x, w1qb, w2q, out);
}